// Round 1
// baseline (984.206 us; speedup 1.0000x reference)
//
#include <hip/hip_runtime.h>
#include <hip/hip_bf16.h>

// ---- problem constants ----
#define VOCAB 32000
#define EMB   256
#define DEC   1024
#define ENC   1024
#define BB    128
#define SS    512
#define MTOT  (BB * SS)      // 65536
#define XCOLS (ENC + EMB)    // 1280
#define NG    (4 * DEC)      // 4096

typedef _Float16 half8  __attribute__((ext_vector_type(8)));
typedef _Float16 half4  __attribute__((ext_vector_type(4)));
typedef float    floatx4 __attribute__((ext_vector_type(4)));

__device__ __forceinline__ float fast_tanh(float x) {
    // tanh(x) = 1 - 2/(e^{2x}+1); exp2-based, safe at +-inf extremes
    float e = __builtin_amdgcn_exp2f(x * 2.885390082f); // e^(2x)
    return 1.0f - 2.0f * __builtin_amdgcn_rcpf(e + 1.0f);
}
__device__ __forceinline__ float fast_sigmoid(float x) {
    float e = __builtin_amdgcn_exp2f(-x * 1.442695041f); // e^(-x)
    return __builtin_amdgcn_rcpf(1.0f + e);
}

// ---- K0: W1 (K=ENC, N=DEC) fp32 -> w1t f16 [n][k] ----
__global__ void k_transpose_w1(const float* __restrict__ W1, _Float16* __restrict__ w1t) {
    __shared__ float tile[32][33];
    const int k0 = blockIdx.y * 32, n0 = blockIdx.x * 32;
    const int tx = threadIdx.x, ty = threadIdx.y; // (32,8)
    #pragma unroll
    for (int j = 0; j < 4; ++j)
        tile[ty + j * 8][tx] = W1[(size_t)(k0 + ty + j * 8) * DEC + n0 + tx];
    __syncthreads();
    #pragma unroll
    for (int j = 0; j < 4; ++j)
        w1t[(size_t)(n0 + ty + j * 8) * ENC + k0 + tx] = (_Float16)tile[tx][ty + j * 8];
}

// ---- K1: hp[b][n] = dh[b]@W2[:,n] + b2[n] + b1[n] ----
__global__ void k_hidden_proj(const float* __restrict__ dh, const float* __restrict__ W2,
                              const float* __restrict__ b1, const float* __restrict__ b2,
                              float* __restrict__ hp) {
    __shared__ float xs[8 * 1024];
    const int t = threadIdx.x;                 // 128
    const int n = blockIdx.x * 128 + t;        // 8 n-tiles
    const int b0 = blockIdx.y * 8;             // 16 b-tiles
    for (int i = t; i < 2048; i += 128)
        ((floatx4*)xs)[i] = ((const floatx4*)(dh + (size_t)b0 * 1024))[i];
    __syncthreads();
    float acc[8] = {0, 0, 0, 0, 0, 0, 0, 0};
    for (int k = 0; k < 1024; ++k) {
        float wval = W2[(size_t)k * 1024 + n];
        #pragma unroll
        for (int j = 0; j < 8; ++j) acc[j] += xs[j * 1024 + k] * wval;
    }
    const float bias = b1[n] + b2[n];
    #pragma unroll
    for (int j = 0; j < 8; ++j) hp[(size_t)(b0 + j) * 1024 + n] = acc[j] + bias;
}

// ---- K2: score[m] = sum_n tanh(enc[m]@W1[:,n] + hp[b][n]) * Wv[n]  (f16 MFMA) ----
// grid (8 n-tiles fastest, 512 m-tiles), block 256. BM=BN=128, BK=32.
__global__ __launch_bounds__(256) void k_score(
    const float* __restrict__ enc, const _Float16* __restrict__ w1t,
    const float* __restrict__ hp, const float* __restrict__ wv,
    float* __restrict__ scores)
{
    __shared__ _Float16 As[128 * 40];
    __shared__ _Float16 Bs[128 * 40];
    const int n0 = blockIdx.x * 128;
    const int m0 = blockIdx.y * 128;
    const int b  = m0 >> 9;                     // m-tile lies in one batch row
    const int t = threadIdx.x;
    const int lane = t & 63, w = t >> 6;
    const int wm = (w >> 1) * 64, wn = (w & 1) * 64;
    const int col = lane & 15, q = lane >> 4;

    floatx4 acc[4][4];
    #pragma unroll
    for (int i = 0; i < 4; ++i)
        #pragma unroll
        for (int j = 0; j < 4; ++j) acc[i][j] = (floatx4){0.f, 0.f, 0.f, 0.f};

    const int sr = t >> 1;                      // staging row 0..127
    const int sc = (t & 1) * 16;                // k-half
    const float*    ag = enc + (size_t)(m0 + sr) * ENC + sc;
    const _Float16* bg = w1t + (size_t)(n0 + sr) * ENC + sc;
    _Float16* asw = &As[sr * 40 + sc];
    _Float16* bsw = &Bs[sr * 40 + sc];

    for (int k0 = 0; k0 < ENC; k0 += 32) {
        __syncthreads();
        floatx4 a0 = *(const floatx4*)(ag + k0);
        floatx4 a1 = *(const floatx4*)(ag + k0 + 4);
        floatx4 a2 = *(const floatx4*)(ag + k0 + 8);
        floatx4 a3 = *(const floatx4*)(ag + k0 + 12);
        half8 bv0 = *(const half8*)(bg + k0);
        half8 bv1 = *(const half8*)(bg + k0 + 8);
        half8 ha, hb;
        #pragma unroll
        for (int e = 0; e < 4; ++e) { ha[e] = (_Float16)a0[e]; ha[e + 4] = (_Float16)a1[e]; }
        #pragma unroll
        for (int e = 0; e < 4; ++e) { hb[e] = (_Float16)a2[e]; hb[e + 4] = (_Float16)a3[e]; }
        *(half8*)(asw)     = ha;
        *(half8*)(asw + 8) = hb;
        *(half8*)(bsw)     = bv0;
        *(half8*)(bsw + 8) = bv1;
        __syncthreads();
        half8 af[4], bf[4];
        #pragma unroll
        for (int i = 0; i < 4; ++i)
            af[i] = *(const half8*)(&As[(wm + i * 16 + col) * 40 + q * 8]);
        #pragma unroll
        for (int j = 0; j < 4; ++j)
            bf[j] = *(const half8*)(&Bs[(wn + j * 16 + col) * 40 + q * 8]);
        #pragma unroll
        for (int i = 0; i < 4; ++i)
            #pragma unroll
            for (int j = 0; j < 4; ++j)
                acc[i][j] = __builtin_amdgcn_mfma_f32_16x16x32_f16(af[i], bf[j], acc[i][j], 0, 0, 0);
    }

    // epilogue: v = acc + hp; score-row += tanh(v)*Wv, reduced over the 128 n of this block
    float hpv[4], wvv[4];
    #pragma unroll
    for (int j = 0; j < 4; ++j) {
        int n = n0 + wn + j * 16 + col;
        hpv[j] = hp[b * 1024 + n];
        wvv[j] = wv[n];
    }
    #pragma unroll
    for (int i = 0; i < 4; ++i) {
        float rs0 = 0.f, rs1 = 0.f, rs2 = 0.f, rs3 = 0.f;
        #pragma unroll
        for (int j = 0; j < 4; ++j) {
            rs0 += fast_tanh(acc[i][j][0] + hpv[j]) * wvv[j];
            rs1 += fast_tanh(acc[i][j][1] + hpv[j]) * wvv[j];
            rs2 += fast_tanh(acc[i][j][2] + hpv[j]) * wvv[j];
            rs3 += fast_tanh(acc[i][j][3] + hpv[j]) * wvv[j];
        }
        #pragma unroll
        for (int off = 1; off < 16; off <<= 1) { // reduce across the 16 cols (same q-group)
            rs0 += __shfl_xor(rs0, off);
            rs1 += __shfl_xor(rs1, off);
            rs2 += __shfl_xor(rs2, off);
            rs3 += __shfl_xor(rs3, off);
        }
        if (col == 0) {
            const int mrow = m0 + wm + i * 16 + q * 4;
            atomicAdd(&scores[mrow + 0], rs0);
            atomicAdd(&scores[mrow + 1], rs1);
            atomicAdd(&scores[mrow + 2], rs2);
            atomicAdd(&scores[mrow + 3], rs3);
        }
    }
}

// ---- K3: softmax over S per batch row -> aw (d_out); also gather emb into x[:,1024:1280] ----
__global__ void k_softmax_emb(const float* __restrict__ scores, const int* __restrict__ tok,
                              const float* __restrict__ emb, float* __restrict__ aw,
                              float* __restrict__ x) {
    const int b = blockIdx.x, t = threadIdx.x; // 256 threads
    float s0 = scores[b * SS + t];
    float s1 = scores[b * SS + 256 + t];
    float mx = fmaxf(s0, s1);
    for (int off = 32; off; off >>= 1) mx = fmaxf(mx, __shfl_xor(mx, off));
    __shared__ float redm[4], reds[4];
    const int w = t >> 6, lane = t & 63;
    if (lane == 0) redm[w] = mx;
    __syncthreads();
    mx = fmaxf(fmaxf(redm[0], redm[1]), fmaxf(redm[2], redm[3]));
    float e0 = exp2f((s0 - mx) * 1.44269504f);
    float e1 = exp2f((s1 - mx) * 1.44269504f);
    float sm = e0 + e1;
    for (int off = 32; off; off >>= 1) sm += __shfl_xor(sm, off);
    if (lane == 0) reds[w] = sm;
    __syncthreads();
    sm = reds[0] + reds[1] + reds[2] + reds[3];
    const float inv = 1.0f / sm;
    aw[b * SS + t]       = e0 * inv;
    aw[b * SS + 256 + t] = e1 * inv;
    x[(size_t)b * XCOLS + ENC + t] = emb[(size_t)tok[b] * EMB + t];
}

// ---- K4: context[b][e] = sum_s aw[b][s] * enc[b][s][e] -> x[:,0:1024] ----
__global__ void k_context(const float* __restrict__ enc, const float* __restrict__ aw,
                          float* __restrict__ x) {
    const int b = blockIdx.x >> 2;
    const int e = (blockIdx.x & 3) * 256 + threadIdx.x;
    const float* ep = enc + (size_t)b * SS * ENC + e;
    const float* ap = aw + b * SS;
    float acc = 0.f;
    #pragma unroll 8
    for (int s = 0; s < SS; ++s) acc += ap[s] * ep[(size_t)s * ENC];
    x[(size_t)b * XCOLS + e] = acc;
}

// ---- K5: z[b][n] = x[b]@lstm_k[:,n]  (bias added in gates) ----
__global__ void k_lstm(const float* __restrict__ x, const float* __restrict__ lk,
                       float* __restrict__ z) {
    __shared__ float xs[8 * XCOLS]; // 40 KB
    const int t = threadIdx.x;              // 128
    const int n = blockIdx.x * 128 + t;     // 32 n-tiles
    const int b0 = blockIdx.y * 8;          // 16 b-tiles
    for (int i = t; i < 2560; i += 128)
        ((floatx4*)xs)[i] = ((const floatx4*)(x + (size_t)b0 * XCOLS))[i];
    __syncthreads();
    float acc[8] = {0, 0, 0, 0, 0, 0, 0, 0};
    for (int k = 0; k < XCOLS; ++k) {
        float wval = lk[(size_t)k * NG + n];
        #pragma unroll
        for (int j = 0; j < 8; ++j) acc[j] += xs[j * XCOLS + k] * wval;
    }
    #pragma unroll
    for (int j = 0; j < 8; ++j) z[(size_t)(b0 + j) * NG + n] = acc[j];
}

// ---- K6: gates (keras order i,f,g,o; c0=0 so f drops out) ----
__global__ void k_gates(const float* __restrict__ z, const float* __restrict__ lb,
                        float* __restrict__ h_out, float* __restrict__ c_out) {
    const int idx = blockIdx.x * 256 + threadIdx.x; // 131072
    const int b = idx >> 10, d = idx & 1023;
    const float* zb = z + (size_t)b * NG;
    float iv = zb[d]        + lb[d];
    float gv = zb[d + 2048] + lb[d + 2048];
    float ov = zb[d + 3072] + lb[d + 3072];
    float c = fast_sigmoid(iv) * fast_tanh(gv);
    float h = fast_sigmoid(ov) * fast_tanh(c);
    h_out[idx] = h;
    c_out[idx] = c;
}

// ---- K7: logits = h @ fc_W + fc_b  (f16 MFMA, M=128 all batch, BN=128, BK=32) ----
__global__ __launch_bounds__(256) void k_fc(
    const float* __restrict__ hsrc, const float* __restrict__ fcW,
    const float* __restrict__ fcb, float* __restrict__ logits)
{
    __shared__ _Float16 As[128 * 40];
    __shared__ _Float16 Bs[128 * 40];
    const int n0 = blockIdx.x * 128; // 250 blocks
    const int t = threadIdx.x;
    const int lane = t & 63, w = t >> 6;
    const int wm = (w >> 1) * 64, wn = (w & 1) * 64;
    const int col = lane & 15, q = lane >> 4;

    floatx4 acc[4][4];
    #pragma unroll
    for (int i = 0; i < 4; ++i)
        #pragma unroll
        for (int j = 0; j < 4; ++j) acc[i][j] = (floatx4){0.f, 0.f, 0.f, 0.f};

    const int sr = t >> 1, sc = (t & 1) * 16;
    const float* ag = hsrc + (size_t)sr * 1024 + sc;
    _Float16* asw = &As[sr * 40 + sc];
    const int bn = (t & 31) * 4;    // n within tile
    const int bk = (t >> 5) * 4;    // k within BK

    for (int k0 = 0; k0 < 1024; k0 += 32) {
        __syncthreads();
        floatx4 a0 = *(const floatx4*)(ag + k0);
        floatx4 a1 = *(const floatx4*)(ag + k0 + 4);
        floatx4 a2 = *(const floatx4*)(ag + k0 + 8);
        floatx4 a3 = *(const floatx4*)(ag + k0 + 12);
        half8 ha, hb;
        #pragma unroll
        for (int e = 0; e < 4; ++e) { ha[e] = (_Float16)a0[e]; ha[e + 4] = (_Float16)a1[e]; }
        #pragma unroll
        for (int e = 0; e < 4; ++e) { hb[e] = (_Float16)a2[e]; hb[e + 4] = (_Float16)a3[e]; }
        *(half8*)(asw)     = ha;
        *(half8*)(asw + 8) = hb;
        // B: 4k x 4n micro-tile, transpose to [n][k] in LDS
        floatx4 w0 = *(const floatx4*)(fcW + (size_t)(k0 + bk + 0) * VOCAB + n0 + bn);
        floatx4 w1 = *(const floatx4*)(fcW + (size_t)(k0 + bk + 1) * VOCAB + n0 + bn);
        floatx4 w2 = *(const floatx4*)(fcW + (size_t)(k0 + bk + 2) * VOCAB + n0 + bn);
        floatx4 w3 = *(const floatx4*)(fcW + (size_t)(k0 + bk + 3) * VOCAB + n0 + bn);
        #pragma unroll
        for (int c = 0; c < 4; ++c) {
            half4 p = { (_Float16)w0[c], (_Float16)w1[c], (_Float16)w2[c], (_Float16)w3[c] };
            *(half4*)(&Bs[(bn + c) * 40 + bk]) = p;
        }
        __syncthreads();
        half8 af[4], bf[4];
        #pragma unroll
        for (int i = 0; i < 4; ++i)
            af[i] = *(const half8*)(&As[(wm + i * 16 + col) * 40 + q * 8]);
        #pragma unroll
        for (int j = 0; j < 4; ++j)
            bf[j] = *(const half8*)(&Bs[(wn + j * 16 + col) * 40 + q * 8]);
        #pragma unroll
        for (int i = 0; i < 4; ++i)
            #pragma unroll
            for (int j = 0; j < 4; ++j)
                acc[i][j] = __builtin_amdgcn_mfma_f32_16x16x32_f16(af[i], bf[j], acc[i][j], 0, 0, 0);
    }

    float fcbv[4];
    #pragma unroll
    for (int j = 0; j < 4; ++j) fcbv[j] = fcb[n0 + wn + j * 16 + col];
    #pragma unroll
    for (int i = 0; i < 4; ++i)
        #pragma unroll
        for (int j = 0; j < 4; ++j)
            #pragma unroll
            for (int r = 0; r < 4; ++r) {
                const int row = wm + i * 16 + q * 4 + r;
                logits[(size_t)row * VOCAB + n0 + wn + j * 16 + col] = acc[i][j][r] + fcbv[j];
            }
}

extern "C" void kernel_launch(void* const* d_in, const int* in_sizes, int n_in,
                              void* d_out, int out_size, void* d_ws, size_t ws_size,
                              hipStream_t stream) {
    const int*   tok    = (const int*)d_in[0];
    const float* dh     = (const float*)d_in[1];
    const float* enc    = (const float*)d_in[2];
    const float* emb    = (const float*)d_in[3];
    const float* W1     = (const float*)d_in[4];
    const float* b1     = (const float*)d_in[5];
    const float* W2     = (const float*)d_in[6];
    const float* b2     = (const float*)d_in[7];
    const float* Wv     = (const float*)d_in[8];
    // d_in[9] bv: cancels in softmax, unused. d_in[11] lstm_rk: multiplies h0=0, unused.
    const float* lstm_k = (const float*)d_in[10];
    const float* lstm_b = (const float*)d_in[12];
    const float* fc_W   = (const float*)d_in[13];
    const float* fc_b   = (const float*)d_in[14];

    float* out    = (float*)d_out;
    float* logits = out;                                   // 128*32000
    float* h_out  = out + 4096000;                         // 128*1024
    float* c_out  = out + 4096000 + 131072;                // 128*1024
    float* aw     = out + 4096000 + 262144;                // 128*512

    char* ws = (char*)d_ws;
    _Float16* w1t    = (_Float16*)ws;                      // 2 MB
    float*    hp     = (float*)(ws + 2097152);             // 512 KB
    float*    scores = (float*)(ws + 2621440);             // 256 KB
    float*    x      = (float*)(ws + 2883584);             // 640 KB
    float*    z      = (float*)(ws + 3538944);             // 2 MB
    // total ws use: ~5.4 MB

    hipMemsetAsync(scores, 0, MTOT * sizeof(float), stream); // atomicAdd target
    k_transpose_w1<<<dim3(32, 32), dim3(32, 8), 0, stream>>>(W1, w1t);
    k_hidden_proj<<<dim3(8, 16), 128, 0, stream>>>(dh, W2, b1, b2, hp);
    // n-tiles fastest: 8 sharers of each enc A-tile are temporally adjacent (L3-hot)
    k_score<<<dim3(8, 512), 256, 0, stream>>>(enc, w1t, hp, Wv, scores);
    k_softmax_emb<<<128, 256, 0, stream>>>(scores, tok, emb, aw, x);
    k_context<<<512, 256, 0, stream>>>(enc, aw, x);
    k_lstm<<<dim3(32, 16), 128, 0, stream>>>(x, lstm_k, z);
    k_gates<<<512, 256, 0, stream>>>(z, lstm_b, h_out, c_out);
    k_fc<<<250, 256, 0, stream>>>(h_out, fc_W, fc_b, logits);
}